// Round 1
// baseline (1349.270 us; speedup 1.0000x reference)
//
#include <hip/hip_runtime.h>
#include <hip/hip_bf16.h>
#include <math.h>

// LongTermMemory: B=128 queries, D=128, N=1M keys/values (row-normalized fp32).
//   ws  = softmax(ns @ K^T / T) @ V   (ns = l2norm(state))
//   age' = age + sum_b softmax_weights
// Two-pass streaming attention: pass1 computes l_b = sum_n exp(s/T) (no max
// subtraction needed: |dot|<=1 -> logits bounded by ~29, exp fits fp32 easily),
// pass2 recomputes scores, accumulates PV in registers + writes new_age inline.
//
// R1 changes vs previous session (1218 us):
//  - pass1: __launch_bounds__(256,3) (12 waves/CU instead of 8), grid 768.
//  - pass2: V tile prefetched one full tile ahead (coalesced float4 rows into
//    regs), staged to LDS transposed bf16 (vt[d][key]); PV reads V as 4
//    conflict-free ds_read_b128 instead of 32 strided global scalars issued
//    right before the MFMAs that need them.

typedef __attribute__((ext_vector_type(8))) short sh8;     // 8 x bf16 (4 VGPRs)
typedef __attribute__((ext_vector_type(4))) float f32x4;   // MFMA accumulator

#define MFMA16(a, b, c) __builtin_amdgcn_mfma_f32_16x16x32_bf16((a), (b), (c), 0, 0, 0)

static __device__ __forceinline__ unsigned short f2bf(float x) {
  union { float f; unsigned u; } v; v.f = x;
  unsigned r = v.u + 0x7fffu + ((v.u >> 16) & 1u);   // RNE
  return (unsigned short)(r >> 16);
}
static __device__ __forceinline__ float bf2f(unsigned short h) {
  union { float f; unsigned u; } v; v.u = ((unsigned)h) << 16; return v.f;
}

// ---------------------------------------------------------------- normalize
// One block per state row: ns = x / max(||x||, 1e-12), stored as bf16 hi+lo.
__global__ void __launch_bounds__(128) k_norm(const float* __restrict__ es,
                                              unsigned short* __restrict__ nhi,
                                              unsigned short* __restrict__ nlo) {
  int b = blockIdx.x, t = threadIdx.x;
  float x = es[b * 128 + t];
  float s = x * x;
#pragma unroll
  for (int m = 1; m < 64; m <<= 1) s += __shfl_xor(s, m, 64);
  __shared__ float ss[2];
  if ((t & 63) == 0) ss[t >> 6] = s;
  __syncthreads();
  float nrm = sqrtf(ss[0] + ss[1]);
  float nx = x / fmaxf(nrm, 1e-12f);
  unsigned short h = f2bf(nx);
  nhi[b * 128 + t] = h;
  nlo[b * 128 + t] = f2bf(nx - bf2f(h));
}

// ---------------------------------------------------------------- pass 1: l_b
// WG=256 (4 waves). Tile = 64 keys. Wave w owns b-rows [32w,32w+32) (2 MFMA
// m-blocks), all 64 key-cols. Keys staged fp32->regs->bf16->LDS (stride 136
// shorts = 272B: conflict-free b128 access). VGPR est ~164 -> fits 3 waves/EU.
__global__ void __launch_bounds__(256, 3) k_pass1(
    const float* __restrict__ keys,
    const unsigned short* __restrict__ nhi, const unsigned short* __restrict__ nlo,
    float* __restrict__ l_acc, int NT, float scale) {
  __shared__ unsigned short khi[64][136];
  int tid = threadIdx.x;
  int wave = tid >> 6, lane = tid & 63, q = lane >> 4, li = lane & 15;
  int strip = wave * 32;

  // A-frags (states) preloaded to registers, hi+lo split: 64 VGPRs.
  sh8 Ah[2][4], Al[2][4];
#pragma unroll
  for (int mb = 0; mb < 2; ++mb)
#pragma unroll
    for (int kk = 0; kk < 4; ++kk) {
      int row = strip + mb * 16 + li, col = kk * 32 + q * 8;
      Ah[mb][kk] = *(const sh8*)&nhi[row * 128 + col];
      Al[mb][kk] = *(const sh8*)&nlo[row * 128 + col];
    }

  float lac[2][4] = {};                 // per-lane e-sums for its columns
  int row = tid & 63, chunk = tid >> 6; // staging: thread -> (key-row, 32-col chunk)
  float4 kreg[8];

  int t = blockIdx.x;
  if (t < NT) {
    const float4* src = (const float4*)(keys + ((long)(t * 64 + row)) * 128 + chunk * 32);
#pragma unroll
    for (int u = 0; u < 8; ++u) kreg[u] = src[u];
  }
  for (; t < NT; t += gridDim.x) {
    // convert prefetched tile -> LDS bf16
#pragma unroll
    for (int u = 0; u < 4; ++u) {
      float4 f0 = kreg[2 * u], f1 = kreg[2 * u + 1];
      sh8 h;
      h[0] = (short)f2bf(f0.x); h[1] = (short)f2bf(f0.y);
      h[2] = (short)f2bf(f0.z); h[3] = (short)f2bf(f0.w);
      h[4] = (short)f2bf(f1.x); h[5] = (short)f2bf(f1.y);
      h[6] = (short)f2bf(f1.z); h[7] = (short)f2bf(f1.w);
      *(sh8*)&khi[row][chunk * 32 + u * 8] = h;
    }
    __syncthreads();
    int tn = t + gridDim.x;               // prefetch next tile early
    if (tn < NT) {
      const float4* src = (const float4*)(keys + ((long)(tn * 64 + row)) * 128 + chunk * 32);
#pragma unroll
      for (int u = 0; u < 8; ++u) kreg[u] = src[u];
    }
    f32x4 sacc[2][4];
#pragma unroll
    for (int mb = 0; mb < 2; ++mb)
#pragma unroll
      for (int nb = 0; nb < 4; ++nb) sacc[mb][nb] = (f32x4){0.f, 0.f, 0.f, 0.f};
#pragma unroll
    for (int kk = 0; kk < 4; ++kk) {
      sh8 Bf[4];
#pragma unroll
      for (int nb = 0; nb < 4; ++nb) Bf[nb] = *(const sh8*)&khi[nb * 16 + li][kk * 32 + q * 8];
#pragma unroll
      for (int mb = 0; mb < 2; ++mb)
#pragma unroll
        for (int nb = 0; nb < 4; ++nb) {
          sacc[mb][nb] = MFMA16(Ah[mb][kk], Bf[nb], sacc[mb][nb]);
          sacc[mb][nb] = MFMA16(Al[mb][kk], Bf[nb], sacc[mb][nb]);
        }
    }
#pragma unroll
    for (int mb = 0; mb < 2; ++mb)
#pragma unroll
      for (int nb = 0; nb < 4; ++nb)
#pragma unroll
        for (int r = 0; r < 4; ++r) lac[mb][r] += exp2f(sacc[mb][nb][r] * scale);
    __syncthreads();                      // protect LDS rewrite next tile
  }
  // reduce over 16 columns (lane bits 0..3), then one atomic per b-row
#pragma unroll
  for (int mb = 0; mb < 2; ++mb)
#pragma unroll
    for (int r = 0; r < 4; ++r) {
      float v = lac[mb][r];
      v += __shfl_xor(v, 1, 64); v += __shfl_xor(v, 2, 64);
      v += __shfl_xor(v, 4, 64); v += __shfl_xor(v, 8, 64);
      if (li == 0) atomicAdd(&l_acc[strip + mb * 16 + q * 4 + r], v);
    }
}

__global__ void k_invl(const float* __restrict__ l_acc, float* __restrict__ inv_l) {
  int t = threadIdx.x;
  inv_l[t] = 1.0f / l_acc[t];
}

// ---------------------------------------------------------------- pass 2
// Recompute e, accumulate W += e*V (PV MFMA, acc in registers across all
// tiles, per-WG partial written at end), new_age written inline per tile.
// Per-tile schedule (K and V both prefetched one tile ahead in regs):
//   [cvt kreg->khi] bar1 [issue kreg t+1] [cvt vreg->vt transposed]
//   [QK^T] [issue vreg t+1] [exp, P->pbuf, na] bar2 [PV from LDS] [age]
__global__ void __launch_bounds__(256, 2) k_pass2(
    const float* __restrict__ keys, const float* __restrict__ vals,
    const float* __restrict__ age,
    const unsigned short* __restrict__ nhi, const unsigned short* __restrict__ nlo,
    const float* __restrict__ inv_l, float* __restrict__ Wpart,
    float* __restrict__ out_age, int NT, float scale) {
  __shared__ unsigned short khi[64][136];   // 17408 B
  __shared__ unsigned short vt[128][72];    // 18432 B  V^T bf16: vt[d][key]
  __shared__ unsigned short pbuf[128][72];  // 18432 B (P relayout C->A operand)
  __shared__ float nabuf[4][64];            // 1024 B   (total 55296 B)
  int tid = threadIdx.x;
  int wave = tid >> 6, lane = tid & 63, q = lane >> 4, li = lane & 15;
  int strip = wave * 32;

  sh8 Ah[2][4], Al[2][4];
#pragma unroll
  for (int mb = 0; mb < 2; ++mb)
#pragma unroll
    for (int kk = 0; kk < 4; ++kk) {
      int row = strip + mb * 16 + li, col = kk * 32 + q * 8;
      Ah[mb][kk] = *(const sh8*)&nhi[row * 128 + col];
      Al[mb][kk] = *(const sh8*)&nlo[row * 128 + col];
    }
  float il[2][4];
#pragma unroll
  for (int mb = 0; mb < 2; ++mb)
#pragma unroll
    for (int r = 0; r < 4; ++r) il[mb][r] = inv_l[strip + mb * 16 + q * 4 + r];

  f32x4 pacc[8][2];                      // PV acc: all 128 b-rows x 32 d-cols
#pragma unroll
  for (int mm = 0; mm < 8; ++mm)
#pragma unroll
    for (int nb2 = 0; nb2 < 2; ++nb2) pacc[mm][nb2] = (f32x4){0.f, 0.f, 0.f, 0.f};

  int row = tid & 63, chunk = tid >> 6;
  float4 kreg[8], vreg[8];
  int t = blockIdx.x;
  if (t < NT) {
    const float4* ksrc = (const float4*)(keys + ((long)(t * 64 + row)) * 128 + chunk * 32);
    const float4* vsrc = (const float4*)(vals + ((long)(t * 64 + row)) * 128 + chunk * 32);
#pragma unroll
    for (int u = 0; u < 8; ++u) kreg[u] = ksrc[u];
#pragma unroll
    for (int u = 0; u < 8; ++u) vreg[u] = vsrc[u];
  }
  for (; t < NT; t += gridDim.x) {
    // K tile (prefetched) -> khi LDS bf16. Safe pre-bar1: PV of t-1 never
    // touches khi.
#pragma unroll
    for (int u = 0; u < 4; ++u) {
      float4 f0 = kreg[2 * u], f1 = kreg[2 * u + 1];
      sh8 h;
      h[0] = (short)f2bf(f0.x); h[1] = (short)f2bf(f0.y);
      h[2] = (short)f2bf(f0.z); h[3] = (short)f2bf(f0.w);
      h[4] = (short)f2bf(f1.x); h[5] = (short)f2bf(f1.y);
      h[6] = (short)f2bf(f1.z); h[7] = (short)f2bf(f1.w);
      *(sh8*)&khi[row][chunk * 32 + u * 8] = h;
    }
    __syncthreads();                      // bar1: keys staged; PV(t-1) done
    int tn = t + gridDim.x;
    if (tn < NT) {                        // K prefetch for t+1
      const float4* src = (const float4*)(keys + ((long)(tn * 64 + row)) * 128 + chunk * 32);
#pragma unroll
      for (int u = 0; u < 8; ++u) kreg[u] = src[u];
    }
    // V tile (prefetched during t-1) -> vt transposed bf16. Per ds_write_b16
    // instr all 64 lanes hit 128 contiguous bytes = 2 lanes/bank = free.
    // Must be after bar1 (PV of t-1 reads vt); done before bar2 (PV of t).
#pragma unroll
    for (int u = 0; u < 8; ++u) {
      float4 f = vreg[u];
      vt[chunk * 32 + u * 4 + 0][row] = f2bf(f.x);
      vt[chunk * 32 + u * 4 + 1][row] = f2bf(f.y);
      vt[chunk * 32 + u * 4 + 2][row] = f2bf(f.z);
      vt[chunk * 32 + u * 4 + 3][row] = f2bf(f.w);
    }
    // QK^T
    f32x4 sacc[2][4];
#pragma unroll
    for (int mb = 0; mb < 2; ++mb)
#pragma unroll
      for (int nb = 0; nb < 4; ++nb) sacc[mb][nb] = (f32x4){0.f, 0.f, 0.f, 0.f};
#pragma unroll
    for (int kk = 0; kk < 4; ++kk) {
      sh8 Bf[4];
#pragma unroll
      for (int nb = 0; nb < 4; ++nb) Bf[nb] = *(const sh8*)&khi[nb * 16 + li][kk * 32 + q * 8];
#pragma unroll
      for (int mb = 0; mb < 2; ++mb)
#pragma unroll
        for (int nb = 0; nb < 4; ++nb) {
          sacc[mb][nb] = MFMA16(Ah[mb][kk], Bf[nb], sacc[mb][nb]);
          sacc[mb][nb] = MFMA16(Al[mb][kk], Bf[nb], sacc[mb][nb]);
        }
    }
    // V prefetch for t+1: ~1300 cy of exp+PV+next staging cover the latency.
    if (tn < NT) {
      const float4* src = (const float4*)(vals + ((long)(tn * 64 + row)) * 128 + chunk * 32);
#pragma unroll
      for (int u = 0; u < 8; ++u) vreg[u] = src[u];
    }
    // e = exp2(s*scale); P -> LDS (bf16); per-column age partials
    float na[4] = {0.f, 0.f, 0.f, 0.f};
#pragma unroll
    for (int mb = 0; mb < 2; ++mb)
#pragma unroll
      for (int nb = 0; nb < 4; ++nb)
#pragma unroll
        for (int r = 0; r < 4; ++r) {
          float e = exp2f(sacc[mb][nb][r] * scale);
          pbuf[strip + mb * 16 + q * 4 + r][nb * 16 + li] = f2bf(e);
          na[nb] += e * il[mb][r];
        }
#pragma unroll
    for (int nb = 0; nb < 4; ++nb) {
      na[nb] += __shfl_xor(na[nb], 16, 64);
      na[nb] += __shfl_xor(na[nb], 32, 64);
    }
    if (q == 0) {
#pragma unroll
      for (int nb = 0; nb < 4; ++nb) nabuf[wave][nb * 16 + li] = na[nb];
    }
    __syncthreads();                      // bar2: P + vt + na visible
    // PV: wave owns d-cols [32w,32w+32). Vf from vt: 16B-aligned b128,
    // bank = 4*(li+q) mod 32 -> exactly the 8-cycle wave64 minimum.
#pragma unroll
    for (int kk2 = 0; kk2 < 2; ++kk2) {
      sh8 Pf[8];
#pragma unroll
      for (int mm = 0; mm < 8; ++mm) Pf[mm] = *(const sh8*)&pbuf[mm * 16 + li][kk2 * 32 + q * 8];
#pragma unroll
      for (int nb2 = 0; nb2 < 2; ++nb2) {
        sh8 Vf = *(const sh8*)&vt[strip + nb2 * 16 + li][kk2 * 32 + q * 8];
#pragma unroll
        for (int mm = 0; mm < 8; ++mm) pacc[mm][nb2] = MFMA16(Pf[mm], Vf, pacc[mm][nb2]);
      }
    }
    if (tid < 64) {                       // new_age for this tile's 64 keys
      float s = nabuf[0][tid] + nabuf[1][tid] + nabuf[2][tid] + nabuf[3][tid];
      long n = (long)t * 64 + tid;
      out_age[n] = age[n] + s;
    }
  }
  // per-WG W partial (no atomics: 512 adds/elem would serialize at L2)
  float* wp = Wpart + (long)blockIdx.x * 16384;
#pragma unroll
  for (int mm = 0; mm < 8; ++mm)
#pragma unroll
    for (int nb2 = 0; nb2 < 2; ++nb2)
#pragma unroll
      for (int r = 0; r < 4; ++r)
        wp[(mm * 16 + q * 4 + r) * 128 + strip + nb2 * 16 + li] = pacc[mm][nb2][r];
}

// ---------------------------------------------------------------- finalize W
__global__ void __launch_bounds__(256) k_finalize(const float* __restrict__ Wpart,
                                                  const float* __restrict__ inv_l,
                                                  float* __restrict__ out, int nparts) {
  int t = blockIdx.x * 256 + threadIdx.x;  // 16384 outputs
  float s0 = 0.f, s1 = 0.f, s2 = 0.f, s3 = 0.f;
  int p = 0;
  for (; p + 4 <= nparts; p += 4) {
    s0 += Wpart[(long)p * 16384 + t];
    s1 += Wpart[(long)(p + 1) * 16384 + t];
    s2 += Wpart[(long)(p + 2) * 16384 + t];
    s3 += Wpart[(long)(p + 3) * 16384 + t];
  }
  for (; p < nparts; ++p) s0 += Wpart[(long)p * 16384 + t];
  out[t] = (s0 + s1 + s2 + s3) * inv_l[t >> 7];
}

extern "C" void kernel_launch(void* const* d_in, const int* in_sizes, int n_in,
                              void* d_out, int out_size, void* d_ws, size_t ws_size,
                              hipStream_t stream) {
  const float* es   = (const float*)d_in[0];
  const float* keys = (const float*)d_in[1];
  const float* vals = (const float*)d_in[2];
  const float* age  = (const float*)d_in[3];
  int N  = in_sizes[3];
  int NT = N / 64;
  double T = 0.11 - log10((double)N) * 0.01;           // 0.049794... for N=2^20
  float scale = (float)(1.4426950408889634195 / T);    // exp(x/T) = exp2(x*scale)

  char* ws = (char*)d_ws;
  unsigned short* nhi = (unsigned short*)ws;           // 32768 B
  unsigned short* nlo = (unsigned short*)(ws + 32768); // 32768 B
  float* l_acc = (float*)(ws + 65536);                 // 512 B
  float* inv_l = (float*)(ws + 66048);                 // 512 B
  float* Wpart = (float*)(ws + 66560);                 // nparts * 64 KB

  long avail = ((long)ws_size - 66560) / (16384 * 4);
  int grid2 = (int)(avail < 512 ? (avail < 1 ? 1 : avail) : 512);

  float* out_ws  = (float*)d_out;        // [128,128]
  float* out_age = (float*)d_out + 16384;

  hipMemsetAsync(l_acc, 0, 512, stream);
  k_norm<<<128, 128, 0, stream>>>(es, nhi, nlo);
  k_pass1<<<768, 256, 0, stream>>>(keys, nhi, nlo, l_acc, NT, scale);
  k_invl<<<1, 128, 0, stream>>>(l_acc, inv_l);
  k_pass2<<<grid2, 256, 0, stream>>>(keys, vals, age, nhi, nlo, inv_l, Wpart, out_age, NT, scale);
  k_finalize<<<64, 256, 0, stream>>>(Wpart, inv_l, out_ws, grid2);
}